// Round 2
// baseline (647.677 us; speedup 1.0000x reference)
//
#include <hip/hip_runtime.h>
#include <hip/hip_bf16.h>
#include <hip/hip_cooperative_groups.h>

namespace cg = cooperative_groups;

// LocalGNN forward, single cooperative kernel, 4 phases with grid.sync().
// h_{p+1} = D (G+I) D h_p  as  acc = (G+I)bf16 @ (d_j h_p,j)bf16, h = d_i*acc.
// P0: G fp32 -> rowsum/dinv + (G+I) bf16 A-frag (gswz) + hF0 = d*x + W frags.
// P1: prop(hFa) -> hrow1, hFb.   P2: prop(hFb) -> hrow2, hFa.
// P3: prop(hFa) + fused [x,h1,h2,h3] @ W^T + bias.
// gswz tiles are block-private (written and read by the same block).
// B=4, N=4096, DIM=64. fp32 in/out, bf16 MFMA internally.

typedef __attribute__((ext_vector_type(4))) float  floatx4;
typedef __attribute__((ext_vector_type(8))) short  short8;

#define NB 4
#define NN 4096
#define ND 64
#define HF_B 262144   // shorts per batch in hF: 128 kc * 4 c * 64 ln * 8

__device__ __forceinline__ unsigned short f2bf_bits(float v) {
    __hip_bfloat16 b = __float2bfloat16(v);
    return *reinterpret_cast<unsigned short*>(&b);
}
__device__ __forceinline__ float bf2f(unsigned short u) {
    unsigned int x = ((unsigned int)u) << 16;
    return *reinterpret_cast<float*>(&x);
}
__device__ __forceinline__ short8 pack8p(const float* v) {
    short8 r;
#pragma unroll
    for (int j = 0; j < 8; ++j) r[j] = (short)f2bf_bits(v[j]);
    return r;
}

// ---- prop core: MFMA over one 16-row tile -> hsh[half], dl[half] filled.
// Extra __syncthreads at entry guards dl/hsh reuse across grid-stride iters.
#define PROP_CORE(HFIN)                                                              \
    {                                                                                \
        __syncthreads();                                                             \
        const unsigned short* Ap = gswz + ((size_t)tile * 128 + w * 32) * 512 + (size_t)lane * 8;          \
        const unsigned short* Bp = (HFIN) + (size_t)b * HF_B + (size_t)(w * 32) * 2048 + (size_t)lane * 8; \
        floatx4 acc[4];                                                              \
        _Pragma("unroll")                                                            \
        for (int c = 0; c < 4; ++c) acc[c] = (floatx4){0.f, 0.f, 0.f, 0.f};          \
        short8 a_c  = *reinterpret_cast<const short8*>(Ap);                          \
        short8 b0_c = *reinterpret_cast<const short8*>(Bp);                          \
        short8 b1_c = *reinterpret_cast<const short8*>(Bp + 512);                    \
        short8 b2_c = *reinterpret_cast<const short8*>(Bp + 1024);                   \
        short8 b3_c = *reinterpret_cast<const short8*>(Bp + 1536);                   \
        _Pragma("unroll 2")                                                          \
        for (int kc = 0; kc < 32; ++kc) {                                            \
            Ap += 512; Bp += 2048;                                                   \
            short8 a_n  = *reinterpret_cast<const short8*>(Ap);                      \
            short8 b0_n = *reinterpret_cast<const short8*>(Bp);                      \
            short8 b1_n = *reinterpret_cast<const short8*>(Bp + 512);                \
            short8 b2_n = *reinterpret_cast<const short8*>(Bp + 1024);               \
            short8 b3_n = *reinterpret_cast<const short8*>(Bp + 1536);               \
            acc[0] = __builtin_amdgcn_mfma_f32_16x16x32_bf16(a_c, b0_c, acc[0], 0, 0, 0); \
            acc[1] = __builtin_amdgcn_mfma_f32_16x16x32_bf16(a_c, b1_c, acc[1], 0, 0, 0); \
            acc[2] = __builtin_amdgcn_mfma_f32_16x16x32_bf16(a_c, b2_c, acc[2], 0, 0, 0); \
            acc[3] = __builtin_amdgcn_mfma_f32_16x16x32_bf16(a_c, b3_c, acc[3], 0, 0, 0); \
            a_c = a_n; b0_c = b0_n; b1_c = b1_n; b2_c = b2_n; b3_c = b3_n;           \
        }                                                                            \
        if (tl < 16) dl[half][tl] = dinv[b * NN + mt * 16 + tl];                     \
        _Pragma("unroll")                                                            \
        for (int c = 0; c < 4; ++c)                                                  \
            _Pragma("unroll")                                                        \
            for (int r = 0; r < 4; ++r) buf[half][w][q * 4 + r][c * 16 + m] = acc[c][r]; \
        __syncthreads();                                                             \
        _Pragma("unroll")                                                            \
        for (int e = 0; e < 4; ++e) {                                                \
            int idx = e * 256 + tl;                                                  \
            int r = idx >> 6, col = idx & 63;                                        \
            float s = buf[half][0][r][col] + buf[half][1][r][col] +                  \
                      buf[half][2][r][col] + buf[half][3][r][col];                   \
            hsh[half][r][col] = f2bf_bits(dl[half][r] * s);                          \
        }                                                                            \
        __syncthreads();                                                             \
    }

#define PROP_EMIT(HROW, HFOUT)                                                       \
    {                                                                                \
        unsigned short* hp = (HROW) + ((size_t)b * NN + mt * 16) * ND;               \
        _Pragma("unroll")                                                            \
        for (int e = 0; e < 4; ++e) {                                                \
            int idx = e * 256 + tl;                                                  \
            hp[idx] = hsh[half][idx >> 6][idx & 63];                                 \
        }                                                                            \
        if (tl < 128) {                                                              \
            int c = tl >> 5, lnl = tl & 31;                                          \
            int q_loc = lnl >> 4, mm = lnl & 15;                                     \
            int u = mt & 1, kc2 = mt >> 1;                                           \
            int ln = u * 32 + lnl;                                                   \
            float v[8];                                                              \
            _Pragma("unroll")                                                        \
            for (int j = 0; j < 8; ++j) {                                            \
                int lr = q_loc * 8 + j;                                              \
                v[j] = dl[half][lr] * bf2f(hsh[half][lr][c * 16 + mm]);              \
            }                                                                        \
            *reinterpret_cast<short8*>((HFOUT) + (size_t)b * HF_B + ((size_t)(kc2 * 4 + c) * 64 + ln) * 8) = pack8p(v); \
        }                                                                            \
    }

__global__ __launch_bounds__(512, 4) void gnn_all(
    const float* __restrict__ g, const float* __restrict__ x,
    const float* __restrict__ W, const float* __restrict__ bias,
    float* __restrict__ dinv, unsigned short* __restrict__ Wf,
    unsigned short* __restrict__ hFa, unsigned short* __restrict__ hFb,
    unsigned short* __restrict__ hrow1, unsigned short* __restrict__ hrow2,
    unsigned short* __restrict__ gswz, float* __restrict__ out)
{
    cg::grid_group grid = cg::this_grid();
    __shared__ float buf[2][4][16][68];
    __shared__ unsigned short hsh[2][16][64];
    __shared__ float dl[2][16];
    __shared__ float rsum[2][4][16];

    int t = threadIdx.x;
    int half = t >> 8, tl = t & 255;
    int w = tl >> 6, lane = tl & 63;
    int m = lane & 15, q = lane >> 4;
    int stride2 = gridDim.x << 1;

    // ---------------- phase 0: G -> gswz, dinv, hF0, Wf
    for (int tile = blockIdx.x * 2 + half; tile < NB * 256; tile += stride2) {
        int b = tile >> 8, mt = tile & 255;
        const float* rowp = g + ((size_t)b * NN + mt * 16 + m) * NN;
        size_t outbase = (size_t)tile * 128 * 512;
        int i_row = mt * 16 + m;
        float rs = 0.f;
        for (int s0 = 0; s0 < NN; s0 += 512) {
            floatx4 vv[8];
#pragma unroll
            for (int gg = 0; gg < 4; ++gg) {
                int kbase = s0 + (gg * 4 + w) * 32 + q * 8;
                vv[2 * gg]     = *reinterpret_cast<const floatx4*>(rowp + kbase);
                vv[2 * gg + 1] = *reinterpret_cast<const floatx4*>(rowp + kbase + 4);
            }
#pragma unroll
            for (int gg = 0; gg < 4; ++gg) {
                int kcl = gg * 4 + w;
                int kbase = s0 + kcl * 32 + q * 8;
                float v[8];
#pragma unroll
                for (int j = 0; j < 4; ++j) { v[j] = vv[2 * gg][j]; v[4 + j] = vv[2 * gg + 1][j]; }
                float s = 0.f;
#pragma unroll
                for (int j = 0; j < 8; ++j) s += v[j];
                rs += s;                                     // rowsum BEFORE +I
                int dj = i_row - kbase;
                if (dj >= 0 && dj < 8) v[dj] += 1.0f;        // +I
                *reinterpret_cast<short8*>(gswz + outbase + ((size_t)((s0 >> 5) + kcl)) * 512 + (size_t)lane * 8) = pack8p(v);
            }
        }
        rs += __shfl_xor(rs, 16);
        rs += __shfl_xor(rs, 32);
        if (lane < 16) rsum[half][w][lane] = rs;
        __syncthreads();
        if (tl < 16) {
            float tot = rsum[half][0][tl] + rsum[half][1][tl] + rsum[half][2][tl] + rsum[half][3][tl];
            float d = 1.0f / (sqrtf(tot + 1.0f) + 1e-7f);    // +1.0 accounts for I
            dinv[b * NN + mt * 16 + tl] = d;
            dl[half][tl] = d;
        }
        __syncthreads();
        if (tl < 128) {                                      // hF0 = d_j * x_j
            int c = tl >> 5, lnl = tl & 31;
            int q_loc = lnl >> 4, mm = lnl & 15;
            int u = mt & 1, kc2 = mt >> 1;
            int ln = u * 32 + lnl;
            const float* xp = x + ((size_t)b * NN + mt * 16) * ND + c * 16 + mm;
            float v[8];
#pragma unroll
            for (int j = 0; j < 8; ++j) {
                int lr = q_loc * 8 + j;
                v[j] = dl[half][lr] * xp[(size_t)lr * ND];
            }
            *reinterpret_cast<short8*>(hFa + (size_t)b * HF_B + ((size_t)(kc2 * 4 + c) * 64 + ln) * 8) = pack8p(v);
        }
        if (tile == 0) {                                     // W -> B-frag layout
#pragma unroll
            for (int e = 0; e < 8; ++e) {
                int wi = e * 256 + tl;
                int kc2 = wi >> 8, c = (wi >> 6) & 3, ln = wi & 63;
                int mm = ln & 15, qq = ln >> 4;
                float v[8];
#pragma unroll
                for (int j = 0; j < 8; ++j) v[j] = W[(size_t)(c * 16 + mm) * 256 + kc2 * 32 + qq * 8 + j];
                *reinterpret_cast<short8*>(Wf + ((size_t)(kc2 * 4 + c) * 64 + ln) * 8) = pack8p(v);
            }
        }
    }
    grid.sync();
    // ---------------- phase 1
    for (int tile = blockIdx.x * 2 + half; tile < NB * 256; tile += stride2) {
        int b = tile >> 8, mt = tile & 255;
        PROP_CORE(hFa)
        PROP_EMIT(hrow1, hFb)
    }
    grid.sync();
    // ---------------- phase 2
    for (int tile = blockIdx.x * 2 + half; tile < NB * 256; tile += stride2) {
        int b = tile >> 8, mt = tile & 255;
        PROP_CORE(hFb)
        PROP_EMIT(hrow2, hFa)
    }
    grid.sync();
    // ---------------- phase 3 + fused final linear
    for (int tile = blockIdx.x * 2 + half; tile < NB * 256; tile += stride2) {
        int b = tile >> 8, mt = tile & 255;
        PROP_CORE(hFa)
        {
            int grow_r = b * NN + mt * 16 + m;               // A row for this lane
            floatx4 facc = (floatx4){0.f, 0.f, 0.f, 0.f};
#pragma unroll
            for (int p = 0; p < 4; ++p) {
#pragma unroll
                for (int ki = 0; ki < 2; ++ki) {
                    short8 af;
                    if (p == 0) {
                        const float* xp = x + (size_t)grow_r * ND + ki * 32 + q * 8;
                        float v[8];
#pragma unroll
                        for (int j = 0; j < 8; ++j) v[j] = xp[j];
                        af = pack8p(v);
                    } else if (p == 1) {
                        af = *reinterpret_cast<const short8*>(hrow1 + (size_t)grow_r * ND + ki * 32 + q * 8);
                    } else if (p == 2) {
                        af = *reinterpret_cast<const short8*>(hrow2 + (size_t)grow_r * ND + ki * 32 + q * 8);
                    } else {
                        af = *reinterpret_cast<const short8*>(&hsh[half][m][ki * 32 + q * 8]);
                    }
                    int kc2 = p * 2 + ki;
                    short8 bf = *reinterpret_cast<const short8*>(Wf + ((size_t)(kc2 * 4 + w) * 64 + lane) * 8);
                    facc = __builtin_amdgcn_mfma_f32_16x16x32_bf16(af, bf, facc, 0, 0, 0);
                }
            }
            float bb = bias[w * 16 + m];
#pragma unroll
            for (int r = 0; r < 4; ++r) {
                int row = b * NN + mt * 16 + q * 4 + r;
                out[(size_t)row * ND + w * 16 + m] = facc[r] + bb;
            }
        }
    }
}

// ================================================================ fallback (non-cooperative), round-1 kernels
__global__ __launch_bounds__(256, 4) void prep_graph(const float* __restrict__ g,
                                                     const float* __restrict__ x,
                                                     const float* __restrict__ W,
                                                     float* __restrict__ dinv,
                                                     unsigned short* __restrict__ gswz,
                                                     unsigned short* __restrict__ hF0,
                                                     unsigned short* __restrict__ Wf) {
    __shared__ float rsum[4][16];
    __shared__ float dl[16];
    int tt = blockIdx.x;
    int b = tt >> 8, mt = tt & 255;
    int t = threadIdx.x;
    int w = t >> 6, lane = t & 63;
    int m = lane & 15, q = lane >> 4;
    const float* rowp = g + ((size_t)b * NN + mt * 16 + m) * NN;
    size_t outbase = (size_t)tt * 128 * 512;
    int i_row = mt * 16 + m;
    float rs = 0.f;
    for (int s0 = 0; s0 < NN; s0 += 512) {
#pragma unroll
        for (int gg = 0; gg < 4; ++gg) {
            int kcl = gg * 4 + w;
            int kbase = s0 + kcl * 32 + q * 8;
            floatx4 v0 = *reinterpret_cast<const floatx4*>(rowp + kbase);
            floatx4 v1 = *reinterpret_cast<const floatx4*>(rowp + kbase + 4);
            float v[8];
#pragma unroll
            for (int j = 0; j < 4; ++j) { v[j] = v0[j]; v[4 + j] = v1[j]; }
            float s = 0.f;
#pragma unroll
            for (int j = 0; j < 8; ++j) s += v[j];
            rs += s;
            int dj = i_row - kbase;
            if (dj >= 0 && dj < 8) v[dj] += 1.0f;
            *reinterpret_cast<short8*>(gswz + outbase + ((size_t)((s0 >> 5) + kcl)) * 512 + (size_t)lane * 8) = pack8p(v);
        }
    }
    rs += __shfl_xor(rs, 16);
    rs += __shfl_xor(rs, 32);
    if (lane < 16) rsum[w][lane] = rs;
    __syncthreads();
    if (t < 16) {
        float tot = rsum[0][t] + rsum[1][t] + rsum[2][t] + rsum[3][t];
        float d = 1.0f / (sqrtf(tot + 1.0f) + 1e-7f);
        dinv[b * NN + mt * 16 + t] = d;
        dl[t] = d;
    }
    __syncthreads();
    if (t < 128) {
        int c = t >> 5, lnl = t & 31;
        int q_loc = lnl >> 4, mm = lnl & 15;
        int u = mt & 1, kc2 = mt >> 1;
        int ln = u * 32 + lnl;
        const float* xp = x + ((size_t)b * NN + mt * 16) * ND + c * 16 + mm;
        float v[8];
#pragma unroll
        for (int j = 0; j < 8; ++j) {
            int lr = q_loc * 8 + j;
            v[j] = dl[lr] * xp[(size_t)lr * ND];
        }
        *reinterpret_cast<short8*>(hF0 + (size_t)b * HF_B + ((size_t)(kc2 * 4 + c) * 64 + ln) * 8) = pack8p(v);
    }
    if (tt == 0) {
#pragma unroll
        for (int e = 0; e < 8; ++e) {
            int wi = e * 256 + t;
            int kc2 = wi >> 8;
            int c = (wi >> 6) & 3;
            int ln = wi & 63;
            int mm = ln & 15, qq = ln >> 4;
            float v[8];
#pragma unroll
            for (int j = 0; j < 8; ++j) v[j] = W[(size_t)(c * 16 + mm) * 256 + kc2 * 32 + qq * 8 + j];
            *reinterpret_cast<short8*>(Wf + ((size_t)(kc2 * 4 + c) * 64 + ln) * 8) = pack8p(v);
        }
    }
}

#define FB_PROP_MAIN()                                                                   \
    int bid = blockIdx.x;                                                                \
    int b = bid >> 8, mt = bid & 255;                                                    \
    int t = threadIdx.x;                                                                 \
    int w = t >> 6, lane = t & 63;                                                       \
    int m = lane & 15, q = lane >> 4;                                                    \
    const unsigned short* Ap = gswz + ((size_t)(b * 256 + mt) * 128 + w * 32) * 512 + (size_t)lane * 8; \
    const unsigned short* Bp = hFin + (size_t)b * HF_B + (size_t)(w * 32) * 2048 + (size_t)lane * 8;    \
    floatx4 acc[4];                                                                      \
    _Pragma("unroll")                                                                    \
    for (int c = 0; c < 4; ++c) acc[c] = (floatx4){0.f, 0.f, 0.f, 0.f};                  \
    _Pragma("unroll 2")                                                                  \
    for (int kc = 0; kc < 32; ++kc) {                                                    \
        short8 a0 = *reinterpret_cast<const short8*>(Ap);                                \
        short8 b0 = *reinterpret_cast<const short8*>(Bp);                                \
        short8 b1 = *reinterpret_cast<const short8*>(Bp + 512);                          \
        short8 b2 = *reinterpret_cast<const short8*>(Bp + 1024);                         \
        short8 b3 = *reinterpret_cast<const short8*>(Bp + 1536);                         \
        Ap += 512; Bp += 2048;                                                           \
        acc[0] = __builtin_amdgcn_mfma_f32_16x16x32_bf16(a0, b0, acc[0], 0, 0, 0);       \
        acc[1] = __builtin_amdgcn_mfma_f32_16x16x32_bf16(a0, b1, acc[1], 0, 0, 0);       \
        acc[2] = __builtin_amdgcn_mfma_f32_16x16x32_bf16(a0, b2, acc[2], 0, 0, 0);       \
        acc[3] = __builtin_amdgcn_mfma_f32_16x16x32_bf16(a0, b3, acc[3], 0, 0, 0);       \
    }                                                                                    \
    if (t < 16) dl[t] = dinv[b * NN + mt * 16 + t];                                      \
    _Pragma("unroll")                                                                    \
    for (int c = 0; c < 4; ++c)                                                          \
        _Pragma("unroll")                                                                \
        for (int r = 0; r < 4; ++r) buf[w][q * 4 + r][c * 16 + m] = acc[c][r];           \
    __syncthreads();                                                                     \
    _Pragma("unroll")                                                                    \
    for (int e = 0; e < 4; ++e) {                                                        \
        int idx = e * 256 + t;                                                           \
        int r = idx >> 6, col = idx & 63;                                                \
        float s = buf[0][r][col] + buf[1][r][col] + buf[2][r][col] + buf[3][r][col];     \
        hsh[r][col] = f2bf_bits(dl[r] * s);                                              \
    }                                                                                    \
    __syncthreads();

__global__ __launch_bounds__(256, 4) void prop_pass(const unsigned short* __restrict__ gswz,
                                                    const unsigned short* __restrict__ hFin,
                                                    const float* __restrict__ dinv,
                                                    unsigned short* __restrict__ hrow,
                                                    unsigned short* __restrict__ hFout) {
    __shared__ float buf[4][16][68];
    __shared__ unsigned short hsh[16][64];
    __shared__ float dl[16];
    FB_PROP_MAIN()
    {
        unsigned short* hp = hrow + ((size_t)b * NN + mt * 16) * ND;
#pragma unroll
        for (int e = 0; e < 4; ++e) {
            int idx = e * 256 + t;
            hp[idx] = hsh[idx >> 6][idx & 63];
        }
    }
    if (t < 128) {
        int c = t >> 5, lnl = t & 31;
        int q_loc = lnl >> 4, mm = lnl & 15;
        int u = mt & 1, kc2 = mt >> 1;
        int ln = u * 32 + lnl;
        float v[8];
#pragma unroll
        for (int j = 0; j < 8; ++j) {
            int lr = q_loc * 8 + j;
            v[j] = dl[lr] * bf2f(hsh[lr][c * 16 + mm]);
        }
        *reinterpret_cast<short8*>(hFout + (size_t)b * HF_B + ((size_t)(kc2 * 4 + c) * 64 + ln) * 8) = pack8p(v);
    }
}

__global__ __launch_bounds__(256, 4) void prop_final(const unsigned short* __restrict__ gswz,
                                                     const unsigned short* __restrict__ hFin,
                                                     const float* __restrict__ dinv,
                                                     const float* __restrict__ x,
                                                     const unsigned short* __restrict__ hrow1,
                                                     const unsigned short* __restrict__ hrow2,
                                                     const unsigned short* __restrict__ Wf,
                                                     const float* __restrict__ bias,
                                                     float* __restrict__ out) {
    __shared__ float buf[4][16][68];
    __shared__ unsigned short hsh[16][64];
    __shared__ float dl[16];
    FB_PROP_MAIN()
    {
        int grow_r = b * NN + mt * 16 + m;
        floatx4 facc = (floatx4){0.f, 0.f, 0.f, 0.f};
#pragma unroll
        for (int p = 0; p < 4; ++p) {
#pragma unroll
            for (int ki = 0; ki < 2; ++ki) {
                short8 af;
                if (p == 0) {
                    const float* xp = x + (size_t)grow_r * ND + ki * 32 + q * 8;
                    float v[8];
#pragma unroll
                    for (int j = 0; j < 8; ++j) v[j] = xp[j];
                    af = pack8p(v);
                } else if (p == 1) {
                    af = *reinterpret_cast<const short8*>(hrow1 + (size_t)grow_r * ND + ki * 32 + q * 8);
                } else if (p == 2) {
                    af = *reinterpret_cast<const short8*>(hrow2 + (size_t)grow_r * ND + ki * 32 + q * 8);
                } else {
                    af = *reinterpret_cast<const short8*>(&hsh[m][ki * 32 + q * 8]);
                }
                int kc2 = p * 2 + ki;
                short8 bf = *reinterpret_cast<const short8*>(Wf + ((size_t)(kc2 * 4 + w) * 64 + lane) * 8);
                facc = __builtin_amdgcn_mfma_f32_16x16x32_bf16(af, bf, facc, 0, 0, 0);
            }
        }
        float bb = bias[w * 16 + m];
#pragma unroll
        for (int r = 0; r < 4; ++r) {
            int row = b * NN + mt * 16 + q * 4 + r;
            out[(size_t)row * ND + w * 16 + m] = facc[r] + bb;
        }
    }
}

// ================================================================ launch
extern "C" void kernel_launch(void* const* d_in, const int* in_sizes, int n_in,
                              void* d_out, int out_size, void* d_ws, size_t ws_size,
                              hipStream_t stream) {
    const float* x     = (const float*)d_in[0];
    const float* graph = (const float*)d_in[1];
    const float* W     = (const float*)d_in[2];
    const float* bias  = (const float*)d_in[3];
    float* out = (float*)d_out;

    // workspace layout (bytes)
    char* wsp = (char*)d_ws;
    float*          dinv  = (float*)wsp;                         //  64 KB
    unsigned short* Wf    = (unsigned short*)(wsp + (1 << 16));  //  32 KB
    unsigned short* hFa   = (unsigned short*)(wsp + (1 << 17));  //   2 MB
    unsigned short* hFb   = hFa + (size_t)NB * HF_B;             //   2 MB
    unsigned short* hrow1 = hFb + (size_t)NB * HF_B;             //   2 MB
    unsigned short* hrow2 = hrow1 + (size_t)NB * NN * ND;        //   2 MB
    unsigned short* gswz  = hrow2 + (size_t)NB * NN * ND;        // 134 MB

    // cooperative grid size: snap to a divisor of 512 so grid-stride iteration
    // counts match between the two tile-halves of each block (syncthreads safety)
    static int nblk = 0;
    if (nblk == 0) {
        int occ = 0;
        hipError_t qe = hipOccupancyMaxActiveBlocksPerMultiprocessor(&occ, (const void*)gnn_all, 512, 0);
        nblk = (qe == hipSuccess && occ >= 2) ? 512 : 256;
    }

    void* kargs[] = {(void*)&graph, (void*)&x, (void*)&W, (void*)&bias,
                     (void*)&dinv, (void*)&Wf, (void*)&hFa, (void*)&hFb,
                     (void*)&hrow1, (void*)&hrow2, (void*)&gswz, (void*)&out};
    hipError_t e = hipLaunchCooperativeKernel((const void*)gnn_all, dim3(nblk), dim3(512),
                                              kargs, 0, stream);
    if (e != hipSuccess) {
        // fallback: 4-kernel non-cooperative pipeline (round-1 verified)
        prep_graph<<<1024, 256, 0, stream>>>(graph, x, W, dinv, gswz, hFa, Wf);
        prop_pass<<<1024, 256, 0, stream>>>(gswz, hFa, dinv, hrow1, hFb);
        prop_pass<<<1024, 256, 0, stream>>>(gswz, hFb, dinv, hrow2, hFa);
        prop_final<<<1024, 256, 0, stream>>>(gswz, hFa, dinv, x, hrow1, hrow2, Wf, bias, out);
    }
}

// Round 3
// 606.096 us; speedup vs baseline: 1.0686x; 1.0686x over previous
//
#include <hip/hip_runtime.h>
#include <hip/hip_bf16.h>

// LocalGNN forward, 4-kernel pipeline, deep register pipelining.
// h_{p+1} = D (G+I) D h_p  as  acc = (G+I)bf16 @ (d_j h_p,j)bf16, h = d_i*acc.
// K0: G fp32 -> rowsum/dinv + (G+I) bf16 A-frags (gswz) + hF0 = d*x + W frags.
//     2-chunk register double-buffer: next chunk's loads in flight during pack/store.
// K1/K2: prop pass, 4-deep prefetch ring (20KB/wave in flight) -> hrow_p + hF_p.
// K3: prop pass 3 + fused [x,h1,h2,h3] @ W^T + bias epilogue.
// B=4, N=4096, DIM=64. fp32 in/out, bf16 MFMA internally.

typedef __attribute__((ext_vector_type(4))) float  floatx4;
typedef __attribute__((ext_vector_type(8))) short  short8;

#define NB 4
#define NN 4096
#define ND 64
#define HF_B 262144   // shorts per batch in hF: 128 kc * 4 c * 64 ln * 8

__device__ __forceinline__ unsigned short f2bf_bits(float v) {
    __hip_bfloat16 b = __float2bfloat16(v);
    return *reinterpret_cast<unsigned short*>(&b);
}
__device__ __forceinline__ float bf2f(unsigned short u) {
    unsigned int x = ((unsigned int)u) << 16;
    return *reinterpret_cast<float*>(&x);
}
__device__ __forceinline__ short8 pack8p(const float* v) {
    short8 r;
#pragma unroll
    for (int j = 0; j < 8; ++j) r[j] = (short)f2bf_bits(v[j]);
    return r;
}

// ================================================================ K0
// block = tile tt (b, mt16): 16 rows x 4096 cols of G. Register double-buffered:
// thread (w,lane) owns frags (kcl=gg*4+w, ln=lane); chunk k+1's 8 loads issue
// BEFORE chunk k's rowsum/pack/store, so ~16KB/wave stays in flight.
#define PREP_LOAD(DST, CH)                                              \
    _Pragma("unroll")                                                   \
    for (int gg = 0; gg < 4; ++gg) {                                    \
        int kb = (CH) * 512 + (gg * 4 + w) * 32 + q * 8;                \
        DST[2 * gg]     = *reinterpret_cast<const floatx4*>(rowp + kb); \
        DST[2 * gg + 1] = *reinterpret_cast<const floatx4*>(rowp + kb + 4); \
    }
#define PREP_PROC(SRC, CH)                                              \
    _Pragma("unroll")                                                   \
    for (int gg = 0; gg < 4; ++gg) {                                    \
        int kcl = gg * 4 + w;                                           \
        int kbase = (CH) * 512 + kcl * 32 + q * 8;                      \
        float v[8];                                                     \
        _Pragma("unroll")                                               \
        for (int j = 0; j < 4; ++j) { v[j] = SRC[2 * gg][j]; v[4 + j] = SRC[2 * gg + 1][j]; } \
        float s = 0.f;                                                  \
        _Pragma("unroll")                                               \
        for (int j = 0; j < 8; ++j) s += v[j];                          \
        rs += s;                                       /* rowsum BEFORE +I */ \
        int dj = i_row - kbase;                                         \
        if (dj >= 0 && dj < 8) v[dj] += 1.0f;          /* +I */         \
        *reinterpret_cast<short8*>(gswz + outbase + ((size_t)((CH) * 16 + kcl)) * 512 + (size_t)lane * 8) = pack8p(v); \
    }

__global__ __launch_bounds__(256, 4) void prep_graph(const float* __restrict__ g,
                                                     const float* __restrict__ x,
                                                     const float* __restrict__ W,
                                                     float* __restrict__ dinv,
                                                     unsigned short* __restrict__ gswz,
                                                     unsigned short* __restrict__ hF0,
                                                     unsigned short* __restrict__ Wf) {
    __shared__ float rsum[4][16];
    __shared__ float dl[16];
    int tt = blockIdx.x;                 // 0..1023
    int b = tt >> 8, mt = tt & 255;
    int t = threadIdx.x;
    int w = t >> 6, lane = t & 63;
    int m = lane & 15, q = lane >> 4;
    const float* rowp = g + ((size_t)b * NN + mt * 16 + m) * NN;
    size_t outbase = (size_t)tt * 128 * 512;
    int i_row = mt * 16 + m;
    float rs = 0.f;
    floatx4 bufA[8], bufB[8];

    PREP_LOAD(bufA, 0)
    PREP_LOAD(bufB, 1) PREP_PROC(bufA, 0)
    PREP_LOAD(bufA, 2) PREP_PROC(bufB, 1)
    PREP_LOAD(bufB, 3) PREP_PROC(bufA, 2)
    PREP_LOAD(bufA, 4) PREP_PROC(bufB, 3)
    PREP_LOAD(bufB, 5) PREP_PROC(bufA, 4)
    PREP_LOAD(bufA, 6) PREP_PROC(bufB, 5)
    PREP_LOAD(bufB, 7) PREP_PROC(bufA, 6)
    PREP_PROC(bufB, 7)

    // rowsum reduce: lanes {m, m+16, m+32, m+48} hold partials of row m
    rs += __shfl_xor(rs, 16);
    rs += __shfl_xor(rs, 32);
    if (lane < 16) rsum[w][lane] = rs;
    __syncthreads();
    if (t < 16) {
        float tot = rsum[0][t] + rsum[1][t] + rsum[2][t] + rsum[3][t];
        float d = 1.0f / (sqrtf(tot + 1.0f) + 1e-7f);    // +1.0 accounts for I
        dinv[b * NN + mt * 16 + t] = d;
        dl[t] = d;
    }
    __syncthreads();
    // this tile's half-window of hF0 = d_j * x_j  (kc = mt>>1, parity mt&1)
    if (t < 128) {
        int c = t >> 5, lnl = t & 31;
        int q_loc = lnl >> 4, mm = lnl & 15;
        int u = mt & 1, kc2 = mt >> 1;
        int ln = u * 32 + lnl;
        const float* xp = x + ((size_t)b * NN + mt * 16) * ND + c * 16 + mm;
        float v[8];
#pragma unroll
        for (int j = 0; j < 8; ++j) {
            int lr = q_loc * 8 + j;                      // 0..15
            v[j] = dl[lr] * xp[(size_t)lr * ND];
        }
        *reinterpret_cast<short8*>(hF0 + (size_t)b * HF_B + ((size_t)(kc2 * 4 + c) * 64 + ln) * 8) = pack8p(v);
    }
    // W -> B-frag layout (block 0 only): Wf[kc][c][ln][8] = W[c*16+m][kc*32+q*8+j]
    if (tt == 0) {
#pragma unroll
        for (int e = 0; e < 8; ++e) {
            int wi = e * 256 + t;                        // 0..2047
            int kc2 = wi >> 8;
            int c = (wi >> 6) & 3;
            int ln = wi & 63;
            int mm = ln & 15, qq = ln >> 4;
            float v[8];
#pragma unroll
            for (int j = 0; j < 8; ++j) v[j] = W[(size_t)(c * 16 + mm) * 256 + kc2 * 32 + qq * 8 + j];
            *reinterpret_cast<short8*>(Wf + ((size_t)(kc2 * 4 + c) * 64 + ln) * 8) = pack8p(v);
        }
    }
}

// ================================================================ prop core
// block = one 16-row tile, wave w = K-chunk [w*1024,(w+1)*1024): 32 kc iters.
// 4-deep prefetch ring, statically indexed (unroll 4): 20 loads (20KB/wave)
// in flight; compiler emits counted vmcnt waits, never a full drain.
// Tail prefetches over-read <=16KB into adjacent workspace regions (safe: d_ws).
#define PROP_MAIN()                                                                      \
    int bid = blockIdx.x;                                                                \
    int b = bid >> 8, mk = bid & 255;                                                    \
    int t = threadIdx.x;                                                                 \
    int w = t >> 6, lane = t & 63;                                                       \
    int m = lane & 15, q = lane >> 4;                                                    \
    const unsigned short* Ap = gswz + ((size_t)(b * 256 + mk) * 128 + w * 32) * 512 + (size_t)lane * 8; \
    const unsigned short* Bp = hFin + (size_t)b * HF_B + (size_t)(w * 32) * 2048 + (size_t)lane * 8;    \
    floatx4 acc[4];                                                                      \
    _Pragma("unroll")                                                                    \
    for (int c = 0; c < 4; ++c) acc[c] = (floatx4){0.f, 0.f, 0.f, 0.f};                  \
    short8 ab[4], bb0[4], bb1[4], bb2[4], bb3[4];                                        \
    _Pragma("unroll")                                                                    \
    for (int p = 0; p < 4; ++p) {                                                        \
        size_t ao = (size_t)p * 512, bo = (size_t)p * 2048;                              \
        ab[p]  = *reinterpret_cast<const short8*>(Ap + ao);                              \
        bb0[p] = *reinterpret_cast<const short8*>(Bp + bo);                              \
        bb1[p] = *reinterpret_cast<const short8*>(Bp + bo + 512);                        \
        bb2[p] = *reinterpret_cast<const short8*>(Bp + bo + 1024);                       \
        bb3[p] = *reinterpret_cast<const short8*>(Bp + bo + 1536);                       \
    }                                                                                    \
    _Pragma("unroll 4")                                                                  \
    for (int kc = 0; kc < 32; ++kc) {                                                    \
        int s = kc & 3;                                                                  \
        acc[0] = __builtin_amdgcn_mfma_f32_16x16x32_bf16(ab[s], bb0[s], acc[0], 0, 0, 0); \
        acc[1] = __builtin_amdgcn_mfma_f32_16x16x32_bf16(ab[s], bb1[s], acc[1], 0, 0, 0); \
        acc[2] = __builtin_amdgcn_mfma_f32_16x16x32_bf16(ab[s], bb2[s], acc[2], 0, 0, 0); \
        acc[3] = __builtin_amdgcn_mfma_f32_16x16x32_bf16(ab[s], bb3[s], acc[3], 0, 0, 0); \
        size_t ao = (size_t)(kc + 4) * 512, bo = (size_t)(kc + 4) * 2048;                \
        ab[s]  = *reinterpret_cast<const short8*>(Ap + ao);                              \
        bb0[s] = *reinterpret_cast<const short8*>(Bp + bo);                              \
        bb1[s] = *reinterpret_cast<const short8*>(Bp + bo + 512);                        \
        bb2[s] = *reinterpret_cast<const short8*>(Bp + bo + 1024);                       \
        bb3[s] = *reinterpret_cast<const short8*>(Bp + bo + 1536);                       \
    }                                                                                    \
    if (t < 16) dl[t] = dinv[b * NN + mk * 16 + t];                                      \
    _Pragma("unroll")                                                                    \
    for (int c = 0; c < 4; ++c)                                                          \
        _Pragma("unroll")                                                                \
        for (int r = 0; r < 4; ++r) buf[w][q * 4 + r][c * 16 + m] = acc[c][r];           \
    __syncthreads();                                                                     \
    _Pragma("unroll")                                                                    \
    for (int e = 0; e < 4; ++e) {                                                        \
        int idx = e * 256 + t;                                                           \
        int r = idx >> 6, col = idx & 63;                                                \
        float s = buf[0][r][col] + buf[1][r][col] + buf[2][r][col] + buf[3][r][col];     \
        hsh[r][col] = f2bf_bits(dl[r] * s);                                              \
    }                                                                                    \
    __syncthreads();

// K1/K2: emit hrow_p + hF_p
__global__ __launch_bounds__(256, 4) void prop_pass(const unsigned short* __restrict__ gswz,
                                                    const unsigned short* __restrict__ hFin,
                                                    const float* __restrict__ dinv,
                                                    unsigned short* __restrict__ hrow,
                                                    unsigned short* __restrict__ hFout) {
    __shared__ float buf[4][16][68];
    __shared__ unsigned short hsh[16][64];
    __shared__ float dl[16];
    PROP_MAIN()
    // hrow: coalesced bf16 store of 16x64
    {
        unsigned short* hp = hrow + ((size_t)b * NN + mk * 16) * ND;
#pragma unroll
        for (int e = 0; e < 4; ++e) {
            int idx = e * 256 + t;
            hp[idx] = hsh[idx >> 6][idx & 63];
        }
    }
    // hF: half-window kc = mk>>1, parity mk&1; value = d_j * h_j
    if (t < 128) {
        int c = t >> 5, lnl = t & 31;
        int q_loc = lnl >> 4, mm = lnl & 15;
        int u = mk & 1, kc2 = mk >> 1;
        int ln = u * 32 + lnl;
        float v[8];
#pragma unroll
        for (int j = 0; j < 8; ++j) {
            int lr = q_loc * 8 + j;                      // 0..15
            v[j] = dl[lr] * bf2f(hsh[lr][c * 16 + mm]);
        }
        *reinterpret_cast<short8*>(hFout + (size_t)b * HF_B + ((size_t)(kc2 * 4 + c) * 64 + ln) * 8) = pack8p(v);
    }
}

// K3: pass 3 + fused final linear: out = [x,h1,h2,h3] @ W^T + bias
// wave w owns output col-block w (16 cols), full K=256 per wave -> no reduce.
__global__ __launch_bounds__(256, 4) void prop_final(const unsigned short* __restrict__ gswz,
                                                     const unsigned short* __restrict__ hFin,
                                                     const float* __restrict__ dinv,
                                                     const float* __restrict__ x,
                                                     const unsigned short* __restrict__ hrow1,
                                                     const unsigned short* __restrict__ hrow2,
                                                     const unsigned short* __restrict__ Wf,
                                                     const float* __restrict__ bias,
                                                     float* __restrict__ out) {
    __shared__ float buf[4][16][68];
    __shared__ unsigned short hsh[16][64];
    __shared__ float dl[16];
    PROP_MAIN()
    {
        int grow_r = b * NN + mk * 16 + m;               // A row for this lane
        floatx4 facc = (floatx4){0.f, 0.f, 0.f, 0.f};
#pragma unroll
        for (int p = 0; p < 4; ++p) {
#pragma unroll
            for (int ki = 0; ki < 2; ++ki) {
                short8 af;
                if (p == 0) {
                    const float* xp = x + (size_t)grow_r * ND + ki * 32 + q * 8;
                    float v[8];
#pragma unroll
                    for (int j = 0; j < 8; ++j) v[j] = xp[j];
                    af = pack8p(v);
                } else if (p == 1) {
                    af = *reinterpret_cast<const short8*>(hrow1 + (size_t)grow_r * ND + ki * 32 + q * 8);
                } else if (p == 2) {
                    af = *reinterpret_cast<const short8*>(hrow2 + (size_t)grow_r * ND + ki * 32 + q * 8);
                } else {
                    af = *reinterpret_cast<const short8*>(&hsh[m][ki * 32 + q * 8]);
                }
                int kc2 = p * 2 + ki;
                short8 bf = *reinterpret_cast<const short8*>(Wf + ((size_t)(kc2 * 4 + w) * 64 + lane) * 8);
                facc = __builtin_amdgcn_mfma_f32_16x16x32_bf16(af, bf, facc, 0, 0, 0);
            }
        }
        float bb = bias[w * 16 + m];
#pragma unroll
        for (int r = 0; r < 4; ++r) {
            int row = b * NN + mk * 16 + q * 4 + r;
            out[(size_t)row * ND + w * 16 + m] = facc[r] + bb;
        }
    }
}

// ================================================================ launch
extern "C" void kernel_launch(void* const* d_in, const int* in_sizes, int n_in,
                              void* d_out, int out_size, void* d_ws, size_t ws_size,
                              hipStream_t stream) {
    const float* x     = (const float*)d_in[0];
    const float* graph = (const float*)d_in[1];
    const float* W     = (const float*)d_in[2];
    const float* bias  = (const float*)d_in[3];
    float* out = (float*)d_out;

    // workspace layout (bytes)
    char* wsp = (char*)d_ws;
    float*          dinv  = (float*)wsp;                         //  64 KB
    unsigned short* Wf    = (unsigned short*)(wsp + (1 << 16));  //  16 KB
    unsigned short* hFa   = (unsigned short*)(wsp + (1 << 17));  //   2 MB
    unsigned short* hFb   = hFa + (size_t)NB * HF_B;             //   2 MB
    unsigned short* hrow1 = hFb + (size_t)NB * HF_B;             //   2 MB
    unsigned short* hrow2 = hrow1 + (size_t)NB * NN * ND;        //   2 MB
    unsigned short* gswz  = hrow2 + (size_t)NB * NN * ND;        // 134 MB

    prep_graph<<<1024, 256, 0, stream>>>(graph, x, W, dinv, gswz, hFa, Wf);
    prop_pass<<<1024, 256, 0, stream>>>(gswz, hFa, dinv, hrow1, hFb);
    prop_pass<<<1024, 256, 0, stream>>>(gswz, hFb, dinv, hrow2, hFa);
    prop_final<<<1024, 256, 0, stream>>>(gswz, hFa, dinv, x, hrow1, hrow2, Wf, bias, out);
}

// Round 4
// 491.192 us; speedup vs baseline: 1.3186x; 1.2339x over previous
//
#include <hip/hip_runtime.h>
#include <hip/hip_bf16.h>

// LocalGNN forward, 4-kernel pipeline.
// h_{p+1} = D (G+I) D h_p  as  acc = (G+I)bf16 @ (d_j h_p,j)bf16, h = d_i*acc.
// K0: G fp32 -> rowsum/dinv + (G+I) bf16 A-frags (gswz) + hF0 = d*x + W frags.
//     Register double-buffer; +I applied with STATIC indices (no scratch demotion).
// K1/K2: prop pass, fully-unrolled 32-iter MFMA loop (no local arrays) -> hrow_p, hF_p.
// K3: prop pass 3 + fused [x,h1,h2,h3] @ W^T + bias epilogue.
// B=4, N=4096, DIM=64. fp32 in/out, bf16 MFMA internally.

typedef __attribute__((ext_vector_type(4))) float  floatx4;
typedef __attribute__((ext_vector_type(8))) short  short8;

#define NB 4
#define NN 4096
#define ND 64
#define HF_B 262144   // shorts per batch in hF: 128 kc * 4 c * 64 ln * 8

__device__ __forceinline__ unsigned short f2bf_bits(float v) {
    __hip_bfloat16 b = __float2bfloat16(v);
    return *reinterpret_cast<unsigned short*>(&b);
}
__device__ __forceinline__ float bf2f(unsigned short u) {
    unsigned int x = ((unsigned int)u) << 16;
    return *reinterpret_cast<float*>(&x);
}
__device__ __forceinline__ short8 pack8p(const float* v) {
    short8 r;
#pragma unroll
    for (int j = 0; j < 8; ++j) r[j] = (short)f2bf_bits(v[j]);
    return r;
}

// ================================================================ K0
// block = tile tt (b, mt16): 16 rows x 4096 cols of G. Register double-buffered:
// chunk k+1's 8 loads issue BEFORE chunk k's rowsum/pack/store.
// +I uses static per-element select (runtime v[dj] demotes v to scratch: rule #20,
// measured round 3 as +219MB phantom WRITE_SIZE).
#define PREP_LOAD(DST, CH)                                              \
    _Pragma("unroll")                                                   \
    for (int gg = 0; gg < 4; ++gg) {                                    \
        int kb = (CH) * 512 + (gg * 4 + w) * 32 + q * 8;                \
        DST[2 * gg]     = *reinterpret_cast<const floatx4*>(rowp + kb); \
        DST[2 * gg + 1] = *reinterpret_cast<const floatx4*>(rowp + kb + 4); \
    }
#define PREP_PROC(SRC, CH)                                              \
    _Pragma("unroll")                                                   \
    for (int gg = 0; gg < 4; ++gg) {                                    \
        int kcl = gg * 4 + w;                                           \
        int kbase = (CH) * 512 + kcl * 32 + q * 8;                      \
        float v[8];                                                     \
        _Pragma("unroll")                                               \
        for (int j = 0; j < 8; ++j) {                                   \
            float xv = (j < 4) ? SRC[2 * gg][j] : SRC[2 * gg + 1][j - 4]; \
            rs += xv;                               /* rowsum BEFORE +I */ \
            v[j] = xv + ((kbase + j == i_row) ? 1.0f : 0.0f);   /* +I, static idx */ \
        }                                                               \
        *reinterpret_cast<short8*>(gswz + outbase + ((size_t)((CH) * 16 + kcl)) * 512 + (size_t)lane * 8) = pack8p(v); \
    }

__global__ __launch_bounds__(256, 4) void prep_graph(const float* __restrict__ g,
                                                     const float* __restrict__ x,
                                                     const float* __restrict__ W,
                                                     float* __restrict__ dinv,
                                                     unsigned short* __restrict__ gswz,
                                                     unsigned short* __restrict__ hF0,
                                                     unsigned short* __restrict__ Wf) {
    __shared__ float rsum[4][16];
    __shared__ float dl[16];
    int tt = blockIdx.x;                 // 0..1023
    int b = tt >> 8, mt = tt & 255;
    int t = threadIdx.x;
    int w = t >> 6, lane = t & 63;
    int m = lane & 15, q = lane >> 4;
    const float* rowp = g + ((size_t)b * NN + mt * 16 + m) * NN;
    size_t outbase = (size_t)tt * 128 * 512;
    int i_row = mt * 16 + m;
    float rs = 0.f;
    floatx4 bufA[8], bufB[8];

    PREP_LOAD(bufA, 0)
    PREP_LOAD(bufB, 1) PREP_PROC(bufA, 0)
    PREP_LOAD(bufA, 2) PREP_PROC(bufB, 1)
    PREP_LOAD(bufB, 3) PREP_PROC(bufA, 2)
    PREP_LOAD(bufA, 4) PREP_PROC(bufB, 3)
    PREP_LOAD(bufB, 5) PREP_PROC(bufA, 4)
    PREP_LOAD(bufA, 6) PREP_PROC(bufB, 5)
    PREP_LOAD(bufB, 7) PREP_PROC(bufA, 6)
    PREP_PROC(bufB, 7)

    // rowsum reduce: lanes {m, m+16, m+32, m+48} hold partials of row m
    rs += __shfl_xor(rs, 16);
    rs += __shfl_xor(rs, 32);
    if (lane < 16) rsum[w][lane] = rs;
    __syncthreads();
    if (t < 16) {
        float tot = rsum[0][t] + rsum[1][t] + rsum[2][t] + rsum[3][t];
        float d = 1.0f / (sqrtf(tot + 1.0f) + 1e-7f);    // +1.0 accounts for I
        dinv[b * NN + mt * 16 + t] = d;
        dl[t] = d;
    }
    __syncthreads();
    // this tile's half-window of hF0 = d_j * x_j  (kc = mt>>1, parity mt&1)
    if (t < 128) {
        int c = t >> 5, lnl = t & 31;
        int q_loc = lnl >> 4, mm = lnl & 15;
        int u = mt & 1, kc2 = mt >> 1;
        int ln = u * 32 + lnl;
        const float* xp = x + ((size_t)b * NN + mt * 16) * ND + c * 16 + mm;
        float v[8];
#pragma unroll
        for (int j = 0; j < 8; ++j) {
            int lr = q_loc * 8 + j;                      // 0..15
            v[j] = dl[lr] * xp[(size_t)lr * ND];
        }
        *reinterpret_cast<short8*>(hF0 + (size_t)b * HF_B + ((size_t)(kc2 * 4 + c) * 64 + ln) * 8) = pack8p(v);
    }
    // W -> B-frag layout (block 0 only): Wf[kc][c][ln][8] = W[c*16+m][kc*32+q*8+j]
    if (tt == 0) {
#pragma unroll
        for (int e = 0; e < 8; ++e) {
            int wi = e * 256 + t;                        // 0..2047
            int kc2 = wi >> 8;
            int c = (wi >> 6) & 3;
            int ln = wi & 63;
            int mm = ln & 15, qq = ln >> 4;
            float v[8];
#pragma unroll
            for (int j = 0; j < 8; ++j) v[j] = W[(size_t)(c * 16 + mm) * 256 + kc2 * 32 + qq * 8 + j];
            *reinterpret_cast<short8*>(Wf + ((size_t)(kc2 * 4 + c) * 64 + ln) * 8) = pack8p(v);
        }
    }
}

// ================================================================ prop core
// block = one 16-row tile, wave w = K-chunk [w*1024,(w+1)*1024): 32 kc iters.
// FULL unroll, no local arrays: every load is a fresh SSA value at a static
// offset; scheduler hoists loads ahead of MFMAs up to the 128-VGPR cap and
// emits counted vmcnt waits (no per-iteration drain, no scratch risk).
#define PROP_MAIN()                                                                      \
    int bid = blockIdx.x;                                                                \
    int b = bid >> 8, mk = bid & 255;                                                    \
    int t = threadIdx.x;                                                                 \
    int w = t >> 6, lane = t & 63;                                                       \
    int m = lane & 15, q = lane >> 4;                                                    \
    const unsigned short* Ap = gswz + ((size_t)(b * 256 + mk) * 128 + w * 32) * 512 + (size_t)lane * 8; \
    const unsigned short* Bp = hFin + (size_t)b * HF_B + (size_t)(w * 32) * 2048 + (size_t)lane * 8;    \
    floatx4 acc[4];                                                                      \
    _Pragma("unroll")                                                                    \
    for (int c = 0; c < 4; ++c) acc[c] = (floatx4){0.f, 0.f, 0.f, 0.f};                  \
    _Pragma("unroll")                                                                    \
    for (int kc = 0; kc < 32; ++kc) {                                                    \
        size_t ao = (size_t)kc * 512, bo = (size_t)kc * 2048;                            \
        short8 a0 = *reinterpret_cast<const short8*>(Ap + ao);                           \
        short8 b0 = *reinterpret_cast<const short8*>(Bp + bo);                           \
        short8 b1 = *reinterpret_cast<const short8*>(Bp + bo + 512);                     \
        short8 b2 = *reinterpret_cast<const short8*>(Bp + bo + 1024);                    \
        short8 b3 = *reinterpret_cast<const short8*>(Bp + bo + 1536);                    \
        acc[0] = __builtin_amdgcn_mfma_f32_16x16x32_bf16(a0, b0, acc[0], 0, 0, 0);       \
        acc[1] = __builtin_amdgcn_mfma_f32_16x16x32_bf16(a0, b1, acc[1], 0, 0, 0);       \
        acc[2] = __builtin_amdgcn_mfma_f32_16x16x32_bf16(a0, b2, acc[2], 0, 0, 0);       \
        acc[3] = __builtin_amdgcn_mfma_f32_16x16x32_bf16(a0, b3, acc[3], 0, 0, 0);       \
    }                                                                                    \
    if (t < 16) dl[t] = dinv[b * NN + mk * 16 + t];                                      \
    _Pragma("unroll")                                                                    \
    for (int c = 0; c < 4; ++c)                                                          \
        _Pragma("unroll")                                                                \
        for (int r = 0; r < 4; ++r) buf[w][q * 4 + r][c * 16 + m] = acc[c][r];           \
    __syncthreads();                                                                     \
    _Pragma("unroll")                                                                    \
    for (int e = 0; e < 4; ++e) {                                                        \
        int idx = e * 256 + t;                                                           \
        int r = idx >> 6, col = idx & 63;                                                \
        float s = buf[0][r][col] + buf[1][r][col] + buf[2][r][col] + buf[3][r][col];     \
        hsh[r][col] = f2bf_bits(dl[r] * s);                                              \
    }                                                                                    \
    __syncthreads();

// K1/K2: emit hrow_p + hF_p
__global__ __launch_bounds__(256, 4) void prop_pass(const unsigned short* __restrict__ gswz,
                                                    const unsigned short* __restrict__ hFin,
                                                    const float* __restrict__ dinv,
                                                    unsigned short* __restrict__ hrow,
                                                    unsigned short* __restrict__ hFout) {
    __shared__ float buf[4][16][68];
    __shared__ unsigned short hsh[16][64];
    __shared__ float dl[16];
    PROP_MAIN()
    // hrow: coalesced bf16 store of 16x64
    {
        unsigned short* hp = hrow + ((size_t)b * NN + mk * 16) * ND;
#pragma unroll
        for (int e = 0; e < 4; ++e) {
            int idx = e * 256 + t;
            hp[idx] = hsh[idx >> 6][idx & 63];
        }
    }
    // hF: half-window kc = mk>>1, parity mk&1; value = d_j * h_j
    if (t < 128) {
        int c = t >> 5, lnl = t & 31;
        int q_loc = lnl >> 4, mm = lnl & 15;
        int u = mk & 1, kc2 = mk >> 1;
        int ln = u * 32 + lnl;
        float v[8];
#pragma unroll
        for (int j = 0; j < 8; ++j) {
            int lr = q_loc * 8 + j;                      // 0..15
            v[j] = dl[lr] * bf2f(hsh[lr][c * 16 + mm]);
        }
        *reinterpret_cast<short8*>(hFout + (size_t)b * HF_B + ((size_t)(kc2 * 4 + c) * 64 + ln) * 8) = pack8p(v);
    }
}

// K3: pass 3 + fused final linear: out = [x,h1,h2,h3] @ W^T + bias
// wave w owns output col-block w (16 cols), full K=256 per wave -> no reduce.
__global__ __launch_bounds__(256, 4) void prop_final(const unsigned short* __restrict__ gswz,
                                                     const unsigned short* __restrict__ hFin,
                                                     const float* __restrict__ dinv,
                                                     const float* __restrict__ x,
                                                     const unsigned short* __restrict__ hrow1,
                                                     const unsigned short* __restrict__ hrow2,
                                                     const unsigned short* __restrict__ Wf,
                                                     const float* __restrict__ bias,
                                                     float* __restrict__ out) {
    __shared__ float buf[4][16][68];
    __shared__ unsigned short hsh[16][64];
    __shared__ float dl[16];
    PROP_MAIN()
    {
        int grow_r = b * NN + mk * 16 + m;               // A row for this lane
        floatx4 facc = (floatx4){0.f, 0.f, 0.f, 0.f};
#pragma unroll
        for (int p = 0; p < 4; ++p) {
#pragma unroll
            for (int ki = 0; ki < 2; ++ki) {
                short8 af;
                if (p == 0) {
                    const float* xp = x + (size_t)grow_r * ND + ki * 32 + q * 8;
                    float v[8];
#pragma unroll
                    for (int j = 0; j < 8; ++j) v[j] = xp[j];
                    af = pack8p(v);
                } else if (p == 1) {
                    af = *reinterpret_cast<const short8*>(hrow1 + (size_t)grow_r * ND + ki * 32 + q * 8);
                } else if (p == 2) {
                    af = *reinterpret_cast<const short8*>(hrow2 + (size_t)grow_r * ND + ki * 32 + q * 8);
                } else {
                    af = *reinterpret_cast<const short8*>(&hsh[m][ki * 32 + q * 8]);
                }
                int kc2 = p * 2 + ki;
                short8 bf = *reinterpret_cast<const short8*>(Wf + ((size_t)(kc2 * 4 + w) * 64 + lane) * 8);
                facc = __builtin_amdgcn_mfma_f32_16x16x32_bf16(af, bf, facc, 0, 0, 0);
            }
        }
        float bb = bias[w * 16 + m];
#pragma unroll
        for (int r = 0; r < 4; ++r) {
            int row = b * NN + mk * 16 + q * 4 + r;
            out[(size_t)row * ND + w * 16 + m] = facc[r] + bb;
        }
    }
}

// ================================================================ launch
extern "C" void kernel_launch(void* const* d_in, const int* in_sizes, int n_in,
                              void* d_out, int out_size, void* d_ws, size_t ws_size,
                              hipStream_t stream) {
    const float* x     = (const float*)d_in[0];
    const float* graph = (const float*)d_in[1];
    const float* W     = (const float*)d_in[2];
    const float* bias  = (const float*)d_in[3];
    float* out = (float*)d_out;

    // workspace layout (bytes)
    char* wsp = (char*)d_ws;
    float*          dinv  = (float*)wsp;                         //  64 KB
    unsigned short* Wf    = (unsigned short*)(wsp + (1 << 16));  //  16 KB
    unsigned short* hFa   = (unsigned short*)(wsp + (1 << 17));  //   2 MB
    unsigned short* hFb   = hFa + (size_t)NB * HF_B;             //   2 MB
    unsigned short* hrow1 = hFb + (size_t)NB * HF_B;             //   2 MB
    unsigned short* hrow2 = hrow1 + (size_t)NB * NN * ND;        //   2 MB
    unsigned short* gswz  = hrow2 + (size_t)NB * NN * ND;        // 134 MB

    prep_graph<<<1024, 256, 0, stream>>>(graph, x, W, dinv, gswz, hFa, Wf);
    prop_pass<<<1024, 256, 0, stream>>>(gswz, hFa, dinv, hrow1, hFb);
    prop_pass<<<1024, 256, 0, stream>>>(gswz, hFb, dinv, hrow2, hFa);
    prop_final<<<1024, 256, 0, stream>>>(gswz, hFa, dinv, x, hrow1, hrow2, Wf, bias, out);
}

// Round 5
// 489.355 us; speedup vs baseline: 1.3235x; 1.0038x over previous
//
#include <hip/hip_runtime.h>
#include <hip/hip_bf16.h>

// LocalGNN forward, 4-kernel pipeline.
// h_{p+1} = D (G+I) D h_p  as  acc = (G+I)bf16 @ (d_j h_p,j)bf16, h = d_i*acc.
// K0: G fp32 -> rowsum/dinv + (G+I) bf16 A-frags (gswz) + hF0 = d*x + W frags.
// K1/K2/K3: prop pass via per-wave global_load_lds 2-deep DMA pipeline with
//   counted vmcnt(5) (never drained in-loop) -> MFMA from LDS. Waves independent,
//   no barriers in the K-loop. Epilogue LDS aliased onto staging slots.
// B=4, N=4096, DIM=64. fp32 in/out, bf16 MFMA internally.

typedef __attribute__((ext_vector_type(4))) float  floatx4;
typedef __attribute__((ext_vector_type(8))) short  short8;

#define NB 4
#define NN 4096
#define ND 64
#define HF_B 262144   // shorts per batch in hF: 128 kc * 4 c * 64 ln * 8

__device__ __forceinline__ unsigned short f2bf_bits(float v) {
    __hip_bfloat16 b = __float2bfloat16(v);
    return *reinterpret_cast<unsigned short*>(&b);
}
__device__ __forceinline__ float bf2f(unsigned short u) {
    unsigned int x = ((unsigned int)u) << 16;
    return *reinterpret_cast<float*>(&x);
}
__device__ __forceinline__ short8 pack8p(const float* v) {
    short8 r;
#pragma unroll
    for (int j = 0; j < 8; ++j) r[j] = (short)f2bf_bits(v[j]);
    return r;
}

// async global->LDS DMA, 16B/lane; LDS dest = wave-uniform base + lane*16.
__device__ __forceinline__ void gld16(const unsigned short* g, unsigned short* l) {
    __builtin_amdgcn_global_load_lds(
        (const __attribute__((address_space(1))) unsigned int*)g,
        (__attribute__((address_space(3))) unsigned int*)l, 16, 0, 0);
}

// ================================================================ K0
// block = tile tt (b, mt16): 16 rows x 4096 cols of G. Register double-buffered:
// chunk k+1's 8 loads issue BEFORE chunk k's rowsum/pack/store.
// +I uses static per-element select (runtime v[dj] demotes v to scratch: rule #20,
// measured round 3 as +219MB phantom WRITE_SIZE).
#define PREP_LOAD(DST, CH)                                              \
    _Pragma("unroll")                                                   \
    for (int gg = 0; gg < 4; ++gg) {                                    \
        int kb = (CH) * 512 + (gg * 4 + w) * 32 + q * 8;                \
        DST[2 * gg]     = *reinterpret_cast<const floatx4*>(rowp + kb); \
        DST[2 * gg + 1] = *reinterpret_cast<const floatx4*>(rowp + kb + 4); \
    }
#define PREP_PROC(SRC, CH)                                              \
    _Pragma("unroll")                                                   \
    for (int gg = 0; gg < 4; ++gg) {                                    \
        int kcl = gg * 4 + w;                                           \
        int kbase = (CH) * 512 + kcl * 32 + q * 8;                      \
        float v[8];                                                     \
        _Pragma("unroll")                                               \
        for (int j = 0; j < 8; ++j) {                                   \
            float xv = (j < 4) ? SRC[2 * gg][j] : SRC[2 * gg + 1][j - 4]; \
            rs += xv;                               /* rowsum BEFORE +I */ \
            v[j] = xv + ((kbase + j == i_row) ? 1.0f : 0.0f);   /* +I, static idx */ \
        }                                                               \
        *reinterpret_cast<short8*>(gswz + outbase + ((size_t)((CH) * 16 + kcl)) * 512 + (size_t)lane * 8) = pack8p(v); \
    }

__global__ __launch_bounds__(256, 4) void prep_graph(const float* __restrict__ g,
                                                     const float* __restrict__ x,
                                                     const float* __restrict__ W,
                                                     float* __restrict__ dinv,
                                                     unsigned short* __restrict__ gswz,
                                                     unsigned short* __restrict__ hF0,
                                                     unsigned short* __restrict__ Wf) {
    __shared__ float rsum[4][16];
    __shared__ float dl[16];
    int tt = blockIdx.x;                 // 0..1023
    int b = tt >> 8, mt = tt & 255;
    int t = threadIdx.x;
    int w = t >> 6, lane = t & 63;
    int m = lane & 15, q = lane >> 4;
    const float* rowp = g + ((size_t)b * NN + mt * 16 + m) * NN;
    size_t outbase = (size_t)tt * 128 * 512;
    int i_row = mt * 16 + m;
    float rs = 0.f;
    floatx4 bufA[8], bufB[8];

    PREP_LOAD(bufA, 0)
    PREP_LOAD(bufB, 1) PREP_PROC(bufA, 0)
    PREP_LOAD(bufA, 2) PREP_PROC(bufB, 1)
    PREP_LOAD(bufB, 3) PREP_PROC(bufA, 2)
    PREP_LOAD(bufA, 4) PREP_PROC(bufB, 3)
    PREP_LOAD(bufB, 5) PREP_PROC(bufA, 4)
    PREP_LOAD(bufA, 6) PREP_PROC(bufB, 5)
    PREP_LOAD(bufB, 7) PREP_PROC(bufA, 6)
    PREP_PROC(bufB, 7)

    // rowsum reduce: lanes {m, m+16, m+32, m+48} hold partials of row m
    rs += __shfl_xor(rs, 16);
    rs += __shfl_xor(rs, 32);
    if (lane < 16) rsum[w][lane] = rs;
    __syncthreads();
    if (t < 16) {
        float tot = rsum[0][t] + rsum[1][t] + rsum[2][t] + rsum[3][t];
        float d = 1.0f / (sqrtf(tot + 1.0f) + 1e-7f);    // +1.0 accounts for I
        dinv[b * NN + mt * 16 + t] = d;
        dl[t] = d;
    }
    __syncthreads();
    // this tile's half-window of hF0 = d_j * x_j  (kc = mt>>1, parity mt&1)
    if (t < 128) {
        int c = t >> 5, lnl = t & 31;
        int q_loc = lnl >> 4, mm = lnl & 15;
        int u = mt & 1, kc2 = mt >> 1;
        int ln = u * 32 + lnl;
        const float* xp = x + ((size_t)b * NN + mt * 16) * ND + c * 16 + mm;
        float v[8];
#pragma unroll
        for (int j = 0; j < 8; ++j) {
            int lr = q_loc * 8 + j;                      // 0..15
            v[j] = dl[lr] * xp[(size_t)lr * ND];
        }
        *reinterpret_cast<short8*>(hF0 + (size_t)b * HF_B + ((size_t)(kc2 * 4 + c) * 64 + ln) * 8) = pack8p(v);
    }
    // W -> B-frag layout (block 0 only): Wf[kc][c][ln][8] = W[c*16+m][kc*32+q*8+j]
    if (tt == 0) {
#pragma unroll
        for (int e = 0; e < 8; ++e) {
            int wi = e * 256 + t;                        // 0..2047
            int kc2 = wi >> 8;
            int c = (wi >> 6) & 3;
            int ln = wi & 63;
            int mm = ln & 15, qq = ln >> 4;
            float v[8];
#pragma unroll
            for (int j = 0; j < 8; ++j) v[j] = W[(size_t)(c * 16 + mm) * 256 + kc2 * 32 + qq * 8 + j];
            *reinterpret_cast<short8*>(Wf + ((size_t)(kc2 * 4 + c) * 64 + ln) * 8) = pack8p(v);
        }
    }
}

// ================================================================ prop core
// block = one 16-row tile, wave w = K-chunk [w*1024,(w+1)*1024): 32 kc steps.
// Per step, wave DMAs A(1KB)+B(4KB) into its own LDS slot (5x global_load_lds),
// 2-deep ring: while computing step s, step s+1's 5 DMAs are in flight
// (vmcnt(5), drained to 0 only at the tail). No barriers in the loop.
// LDS: 8 slots x 5120B = 40960B; epilogue buf/hsh/dl aliased on top post-sync.
#define PSTAGE(S, P) {                                                                   \
    int kk_ = w * 32 + (S);                                                              \
    unsigned short* sl_ = slotb + (P) * 2560;                                            \
    const unsigned short* ga_ = gA + (size_t)kk_ * 512 + lane * 8;                       \
    const unsigned short* gb_ = gB + (size_t)kk_ * 2048 + lane * 8;                      \
    gld16(ga_, sl_);                                                                     \
    gld16(gb_, sl_ + 512);                                                               \
    gld16(gb_ + 512, sl_ + 1024);                                                        \
    gld16(gb_ + 1024, sl_ + 1536);                                                       \
    gld16(gb_ + 1536, sl_ + 2048);                                                       \
}

#define PROP_MAIN(HFIN)                                                                  \
    int bid = blockIdx.x;                                                                \
    int b = bid >> 8, mk = bid & 255;                                                    \
    int t = threadIdx.x;                                                                 \
    int w = t >> 6, lane = t & 63;                                                       \
    int m = lane & 15, q = lane >> 4;                                                    \
    float dv = 0.f;                                                                      \
    if (t < 16) dv = dinv[b * NN + mk * 16 + t];     /* reg-held; dl LDS written later */\
    unsigned short* smem_us = (unsigned short*)smemf;                                    \
    float (*buf)[16][68] = (float (*)[16][68])smemf;      /* 17408 B, aliases slots */   \
    unsigned short* hshp = (unsigned short*)(smemf + 4352);  /* 2048 B */                \
    float* dlp = smemf + 4352 + 512;                         /* 64 B */                  \
    const unsigned short* gA = gswz + (size_t)(b * 256 + mk) * 128 * 512;                \
    const unsigned short* gB = (HFIN) + (size_t)b * HF_B;                                \
    unsigned short* slotb = smem_us + w * 5120;                                          \
    floatx4 acc[4];                                                                      \
    _Pragma("unroll")                                                                    \
    for (int c = 0; c < 4; ++c) acc[c] = (floatx4){0.f, 0.f, 0.f, 0.f};                  \
    PSTAGE(0, 0)                                                                         \
    PSTAGE(1, 1)                                                                         \
    _Pragma("unroll")                                                                    \
    for (int s = 0; s < 32; ++s) {                                                       \
        if (s < 31) { asm volatile("s_waitcnt vmcnt(5)" ::: "memory"); }                 \
        else        { asm volatile("s_waitcnt vmcnt(0)" ::: "memory"); }                 \
        const unsigned short* sl = slotb + (s & 1) * 2560;                               \
        short8 a0 = *reinterpret_cast<const short8*>(sl + lane * 8);                     \
        short8 b0 = *reinterpret_cast<const short8*>(sl + 512 + lane * 8);               \
        short8 b1 = *reinterpret_cast<const short8*>(sl + 1024 + lane * 8);              \
        short8 b2 = *reinterpret_cast<const short8*>(sl + 1536 + lane * 8);              \
        short8 b3 = *reinterpret_cast<const short8*>(sl + 2048 + lane * 8);              \
        asm volatile("s_waitcnt lgkmcnt(0)" ::: "memory");  /* reads in regs before slot reuse */ \
        if (s < 30) PSTAGE(s + 2, s & 1)                                                 \
        acc[0] = __builtin_amdgcn_mfma_f32_16x16x32_bf16(a0, b0, acc[0], 0, 0, 0);       \
        acc[1] = __builtin_amdgcn_mfma_f32_16x16x32_bf16(a0, b1, acc[1], 0, 0, 0);       \
        acc[2] = __builtin_amdgcn_mfma_f32_16x16x32_bf16(a0, b2, acc[2], 0, 0, 0);       \
        acc[3] = __builtin_amdgcn_mfma_f32_16x16x32_bf16(a0, b3, acc[3], 0, 0, 0);       \
    }                                                                                    \
    __syncthreads();                      /* all waves done with staging LDS */          \
    if (t < 16) dlp[t] = dv;                                                             \
    _Pragma("unroll")                                                                    \
    for (int c = 0; c < 4; ++c)                                                          \
        _Pragma("unroll")                                                                \
        for (int r = 0; r < 4; ++r) buf[w][q * 4 + r][c * 16 + m] = acc[c][r];           \
    __syncthreads();                                                                     \
    _Pragma("unroll")                                                                    \
    for (int e = 0; e < 4; ++e) {                                                        \
        int idx = e * 256 + t;                                                           \
        int r = idx >> 6, col = idx & 63;                                                \
        float sv = buf[0][r][col] + buf[1][r][col] + buf[2][r][col] + buf[3][r][col];    \
        hshp[r * 64 + col] = f2bf_bits(dlp[r] * sv);                                     \
    }                                                                                    \
    __syncthreads();

// K1/K2: emit hrow_p + hF_p
__global__ __launch_bounds__(256, 4) void prop_pass(const unsigned short* __restrict__ gswz,
                                                    const unsigned short* __restrict__ hFin,
                                                    const float* __restrict__ dinv,
                                                    unsigned short* __restrict__ hrow,
                                                    unsigned short* __restrict__ hFout) {
    __shared__ float smemf[10240];       // 40960 B: 8 staging slots / epilogue alias
    PROP_MAIN(hFin)
    // hrow: coalesced bf16 store of 16x64
    {
        unsigned short* hp = hrow + ((size_t)b * NN + mk * 16) * ND;
#pragma unroll
        for (int e = 0; e < 4; ++e) {
            int idx = e * 256 + t;
            hp[idx] = hshp[idx];
        }
    }
    // hF: half-window kc = mk>>1, parity mk&1; value = d_j * h_j
    if (t < 128) {
        int c = t >> 5, lnl = t & 31;
        int q_loc = lnl >> 4, mm = lnl & 15;
        int u = mk & 1, kc2 = mk >> 1;
        int ln = u * 32 + lnl;
        float v[8];
#pragma unroll
        for (int j = 0; j < 8; ++j) {
            int lr = q_loc * 8 + j;                      // 0..15
            v[j] = dlp[lr] * bf2f(hshp[lr * 64 + c * 16 + mm]);
        }
        *reinterpret_cast<short8*>(hFout + (size_t)b * HF_B + ((size_t)(kc2 * 4 + c) * 64 + ln) * 8) = pack8p(v);
    }
}

// K3: pass 3 + fused final linear: out = [x,h1,h2,h3] @ W^T + bias
// wave w owns output col-block w (16 cols), full K=256 per wave -> no reduce.
__global__ __launch_bounds__(256, 4) void prop_final(const unsigned short* __restrict__ gswz,
                                                     const unsigned short* __restrict__ hFin,
                                                     const float* __restrict__ dinv,
                                                     const float* __restrict__ x,
                                                     const unsigned short* __restrict__ hrow1,
                                                     const unsigned short* __restrict__ hrow2,
                                                     const unsigned short* __restrict__ Wf,
                                                     const float* __restrict__ bias,
                                                     float* __restrict__ out) {
    __shared__ float smemf[10240];
    PROP_MAIN(hFin)
    {
        int grow_r = b * NN + mk * 16 + m;               // A row for this lane
        floatx4 facc = (floatx4){0.f, 0.f, 0.f, 0.f};
#pragma unroll
        for (int p = 0; p < 4; ++p) {
#pragma unroll
            for (int ki = 0; ki < 2; ++ki) {
                short8 af;
                if (p == 0) {
                    const float* xp = x + (size_t)grow_r * ND + ki * 32 + q * 8;
                    float v[8];
#pragma unroll
                    for (int j = 0; j < 8; ++j) v[j] = xp[j];
                    af = pack8p(v);
                } else if (p == 1) {
                    af = *reinterpret_cast<const short8*>(hrow1 + (size_t)grow_r * ND + ki * 32 + q * 8);
                } else if (p == 2) {
                    af = *reinterpret_cast<const short8*>(hrow2 + (size_t)grow_r * ND + ki * 32 + q * 8);
                } else {
                    af = *reinterpret_cast<const short8*>(&hshp[m * 64 + ki * 32 + q * 8]);
                }
                int kc2 = p * 2 + ki;
                short8 bf = *reinterpret_cast<const short8*>(Wf + ((size_t)(kc2 * 4 + w) * 64 + lane) * 8);
                facc = __builtin_amdgcn_mfma_f32_16x16x32_bf16(af, bf, facc, 0, 0, 0);
            }
        }
        float bb = bias[w * 16 + m];
#pragma unroll
        for (int r = 0; r < 4; ++r) {
            int row = b * NN + mk * 16 + q * 4 + r;
            out[(size_t)row * ND + w * 16 + m] = facc[r] + bb;
        }
    }
}

// ================================================================ launch
extern "C" void kernel_launch(void* const* d_in, const int* in_sizes, int n_in,
                              void* d_out, int out_size, void* d_ws, size_t ws_size,
                              hipStream_t stream) {
    const float* x     = (const float*)d_in[0];
    const float* graph = (const float*)d_in[1];
    const float* W     = (const float*)d_in[2];
    const float* bias  = (const float*)d_in[3];
    float* out = (float*)d_out;

    // workspace layout (bytes)
    char* wsp = (char*)d_ws;
    float*          dinv  = (float*)wsp;                         //  64 KB
    unsigned short* Wf    = (unsigned short*)(wsp + (1 << 16));  //  16 KB
    unsigned short* hFa   = (unsigned short*)(wsp + (1 << 17));  //   2 MB
    unsigned short* hFb   = hFa + (size_t)NB * HF_B;             //   2 MB
    unsigned short* hrow1 = hFb + (size_t)NB * HF_B;             //   2 MB
    unsigned short* hrow2 = hrow1 + (size_t)NB * NN * ND;        //   2 MB
    unsigned short* gswz  = hrow2 + (size_t)NB * NN * ND;        // 134 MB

    prep_graph<<<1024, 256, 0, stream>>>(graph, x, W, dinv, gswz, hFa, Wf);
    prop_pass<<<1024, 256, 0, stream>>>(gswz, hFa, dinv, hrow1, hFb);
    prop_pass<<<1024, 256, 0, stream>>>(gswz, hFb, dinv, hrow2, hFa);
    prop_final<<<1024, 256, 0, stream>>>(gswz, hFa, dinv, x, hrow1, hrow2, Wf, bias, out);
}

// Round 6
// 483.303 us; speedup vs baseline: 1.3401x; 1.0125x over previous
//
#include <hip/hip_runtime.h>
#include <hip/hip_bf16.h>

// LocalGNN forward, 4-kernel pipeline.
// h_{p+1} = D (G+I) D h_p  as  acc = (G+I)bf16 @ (d_j h_p,j)bf16, h = d_i*acc.
// K0: G fp32 -> rowsum/dinv + (G+I) bf16 A-frags (gswz) + hF0 = d*x + W frags.
// K1/K2/K3: prop pass, 512 blocks x 32 rows (2 tiles/wave: B-reads amortized 2x),
//   batch-grouping XCD swizzle (hF L2-resident per XCD pair), full-unroll SSA K-loop.
// B=4, N=4096, DIM=64. fp32 in/out, bf16 MFMA internally.

typedef __attribute__((ext_vector_type(4))) float  floatx4;
typedef __attribute__((ext_vector_type(8))) short  short8;

#define NB 4
#define NN 4096
#define ND 64
#define HF_B 262144   // shorts per batch in hF: 128 kc * 4 c * 64 ln * 8

__device__ __forceinline__ unsigned short f2bf_bits(float v) {
    __hip_bfloat16 b = __float2bfloat16(v);
    return *reinterpret_cast<unsigned short*>(&b);
}
__device__ __forceinline__ float bf2f(unsigned short u) {
    unsigned int x = ((unsigned int)u) << 16;
    return *reinterpret_cast<float*>(&x);
}
__device__ __forceinline__ short8 pack8p(const float* v) {
    short8 r;
#pragma unroll
    for (int j = 0; j < 8; ++j) r[j] = (short)f2bf_bits(v[j]);
    return r;
}

// ================================================================ K0
// block = tile tt (b, mt16): 16 rows x 4096 cols of G. Register double-buffered:
// chunk k+1's 8 loads issue BEFORE chunk k's rowsum/pack/store.
// +I uses static per-element select (runtime v[dj] demotes v to scratch: rule #20,
// measured round 3 as +219MB phantom WRITE_SIZE).
#define PREP_LOAD(DST, CH)                                              \
    _Pragma("unroll")                                                   \
    for (int gg = 0; gg < 4; ++gg) {                                    \
        int kb = (CH) * 512 + (gg * 4 + w) * 32 + q * 8;                \
        DST[2 * gg]     = *reinterpret_cast<const floatx4*>(rowp + kb); \
        DST[2 * gg + 1] = *reinterpret_cast<const floatx4*>(rowp + kb + 4); \
    }
#define PREP_PROC(SRC, CH)                                              \
    _Pragma("unroll")                                                   \
    for (int gg = 0; gg < 4; ++gg) {                                    \
        int kcl = gg * 4 + w;                                           \
        int kbase = (CH) * 512 + kcl * 32 + q * 8;                      \
        float v[8];                                                     \
        _Pragma("unroll")                                               \
        for (int j = 0; j < 8; ++j) {                                   \
            float xv = (j < 4) ? SRC[2 * gg][j] : SRC[2 * gg + 1][j - 4]; \
            rs += xv;                               /* rowsum BEFORE +I */ \
            v[j] = xv + ((kbase + j == i_row) ? 1.0f : 0.0f);   /* +I, static idx */ \
        }                                                               \
        *reinterpret_cast<short8*>(gswz + outbase + ((size_t)((CH) * 16 + kcl)) * 512 + (size_t)lane * 8) = pack8p(v); \
    }

__global__ __launch_bounds__(256, 4) void prep_graph(const float* __restrict__ g,
                                                     const float* __restrict__ x,
                                                     const float* __restrict__ W,
                                                     float* __restrict__ dinv,
                                                     unsigned short* __restrict__ gswz,
                                                     unsigned short* __restrict__ hF0,
                                                     unsigned short* __restrict__ Wf) {
    __shared__ float rsum[4][16];
    __shared__ float dl[16];
    int tt = blockIdx.x;                 // 0..1023
    int b = tt >> 8, mt = tt & 255;
    int t = threadIdx.x;
    int w = t >> 6, lane = t & 63;
    int m = lane & 15, q = lane >> 4;
    const float* rowp = g + ((size_t)b * NN + mt * 16 + m) * NN;
    size_t outbase = (size_t)tt * 128 * 512;
    int i_row = mt * 16 + m;
    float rs = 0.f;
    floatx4 bufA[8], bufB[8];

    PREP_LOAD(bufA, 0)
    PREP_LOAD(bufB, 1) PREP_PROC(bufA, 0)
    PREP_LOAD(bufA, 2) PREP_PROC(bufB, 1)
    PREP_LOAD(bufB, 3) PREP_PROC(bufA, 2)
    PREP_LOAD(bufA, 4) PREP_PROC(bufB, 3)
    PREP_LOAD(bufB, 5) PREP_PROC(bufA, 4)
    PREP_LOAD(bufA, 6) PREP_PROC(bufB, 5)
    PREP_LOAD(bufB, 7) PREP_PROC(bufA, 6)
    PREP_PROC(bufB, 7)

    // rowsum reduce: lanes {m, m+16, m+32, m+48} hold partials of row m
    rs += __shfl_xor(rs, 16);
    rs += __shfl_xor(rs, 32);
    if (lane < 16) rsum[w][lane] = rs;
    __syncthreads();
    if (t < 16) {
        float tot = rsum[0][t] + rsum[1][t] + rsum[2][t] + rsum[3][t];
        float d = 1.0f / (sqrtf(tot + 1.0f) + 1e-7f);    // +1.0 accounts for I
        dinv[b * NN + mt * 16 + t] = d;
        dl[t] = d;
    }
    __syncthreads();
    // this tile's half-window of hF0 = d_j * x_j  (kc = mt>>1, parity mt&1)
    if (t < 128) {
        int c = t >> 5, lnl = t & 31;
        int q_loc = lnl >> 4, mm = lnl & 15;
        int u = mt & 1, kc2 = mt >> 1;
        int ln = u * 32 + lnl;
        const float* xp = x + ((size_t)b * NN + mt * 16) * ND + c * 16 + mm;
        float v[8];
#pragma unroll
        for (int j = 0; j < 8; ++j) {
            int lr = q_loc * 8 + j;                      // 0..15
            v[j] = dl[lr] * xp[(size_t)lr * ND];
        }
        *reinterpret_cast<short8*>(hF0 + (size_t)b * HF_B + ((size_t)(kc2 * 4 + c) * 64 + ln) * 8) = pack8p(v);
    }
    // W -> B-frag layout (block 0 only): Wf[kc][c][ln][8] = W[c*16+m][kc*32+q*8+j]
    if (tt == 0) {
#pragma unroll
        for (int e = 0; e < 8; ++e) {
            int wi = e * 256 + t;                        // 0..2047
            int kc2 = wi >> 8;
            int c = (wi >> 6) & 3;
            int ln = wi & 63;
            int mm = ln & 15, qq = ln >> 4;
            float v[8];
#pragma unroll
            for (int j = 0; j < 8; ++j) v[j] = W[(size_t)(c * 16 + mm) * 256 + kc2 * 32 + qq * 8 + j];
            *reinterpret_cast<short8*>(Wf + ((size_t)(kc2 * 4 + c) * 64 + ln) * 8) = pack8p(v);
        }
    }
}

// ================================================================ prop core
// block = 32 rows (2 tiles), wave w = K-chunk [w*1024,(w+1)*1024): 32 kc iters.
// Each wave's B-frags feed BOTH tiles (B global traffic halved vs 1-tile).
// XCD swizzle groups each batch onto one XCD pair: per-L2 hot hF = 512 KB
// (vs 2 MB unswizzled) -> B reads stay L2-resident under gswz streaming.
// Full unroll, SSA loads: compiler hoists loads, counted vmcnt, no scratch.
#define PROP_MAIN()                                                                      \
    int bid0 = blockIdx.x;                                                               \
    int lid = ((bid0 & 7) << 6) + (bid0 >> 3);      /* 512%8==0: bijective */            \
    int b = lid >> 7, mk = lid & 127;                                                    \
    int t = threadIdx.x;                                                                 \
    int w = t >> 6, lane = t & 63;                                                       \
    int m = lane & 15, q = lane >> 4;                                                    \
    int tt0 = b * 256 + mk * 2;                                                          \
    const unsigned short* Ap0 = gswz + ((size_t)tt0 * 128 + w * 32) * 512 + (size_t)lane * 8; \
    const unsigned short* Ap1 = Ap0 + (size_t)128 * 512;                                 \
    const unsigned short* Bp  = hFin + (size_t)b * HF_B + (size_t)(w * 32) * 2048 + (size_t)lane * 8; \
    floatx4 acc0[4], acc1[4];                                                            \
    _Pragma("unroll")                                                                    \
    for (int c = 0; c < 4; ++c) { acc0[c] = (floatx4){0.f,0.f,0.f,0.f}; acc1[c] = acc0[c]; } \
    _Pragma("unroll")                                                                    \
    for (int kc = 0; kc < 32; ++kc) {                                                    \
        size_t ao = (size_t)kc * 512, bo = (size_t)kc * 2048;                            \
        short8 a0 = *reinterpret_cast<const short8*>(Ap0 + ao);                          \
        short8 a1 = *reinterpret_cast<const short8*>(Ap1 + ao);                          \
        short8 b0 = *reinterpret_cast<const short8*>(Bp + bo);                           \
        short8 b1 = *reinterpret_cast<const short8*>(Bp + bo + 512);                     \
        short8 b2 = *reinterpret_cast<const short8*>(Bp + bo + 1024);                    \
        short8 b3 = *reinterpret_cast<const short8*>(Bp + bo + 1536);                    \
        acc0[0] = __builtin_amdgcn_mfma_f32_16x16x32_bf16(a0, b0, acc0[0], 0, 0, 0);     \
        acc1[0] = __builtin_amdgcn_mfma_f32_16x16x32_bf16(a1, b0, acc1[0], 0, 0, 0);     \
        acc0[1] = __builtin_amdgcn_mfma_f32_16x16x32_bf16(a0, b1, acc0[1], 0, 0, 0);     \
        acc1[1] = __builtin_amdgcn_mfma_f32_16x16x32_bf16(a1, b1, acc1[1], 0, 0, 0);     \
        acc0[2] = __builtin_amdgcn_mfma_f32_16x16x32_bf16(a0, b2, acc0[2], 0, 0, 0);     \
        acc1[2] = __builtin_amdgcn_mfma_f32_16x16x32_bf16(a1, b2, acc1[2], 0, 0, 0);     \
        acc0[3] = __builtin_amdgcn_mfma_f32_16x16x32_bf16(a0, b3, acc0[3], 0, 0, 0);     \
        acc1[3] = __builtin_amdgcn_mfma_f32_16x16x32_bf16(a1, b3, acc1[3], 0, 0, 0);     \
    }                                                                                    \
    if (t < 32) dl[t] = dinv[b * NN + mk * 32 + t];                                      \
    for (int u = 0; u < 2; ++u) {                                                        \
        __syncthreads();                                                                 \
        floatx4* acc = u ? acc1 : acc0;                                                  \
        _Pragma("unroll")                                                                \
        for (int c = 0; c < 4; ++c)                                                      \
            _Pragma("unroll")                                                            \
            for (int r = 0; r < 4; ++r) buf[w][q * 4 + r][c * 16 + m] = acc[c][r];       \
        __syncthreads();                                                                 \
        _Pragma("unroll")                                                                \
        for (int e = 0; e < 4; ++e) {                                                    \
            int idx = e * 256 + t;                                                       \
            int r = idx >> 6, col = idx & 63;                                            \
            float s = buf[0][r][col] + buf[1][r][col] + buf[2][r][col] + buf[3][r][col]; \
            int lr = u * 16 + r;                                                         \
            hsh[lr][col] = f2bf_bits(dl[lr] * s);                                        \
        }                                                                                \
    }                                                                                    \
    __syncthreads();

// K1/K2: emit hrow_p + hF_p
__global__ __launch_bounds__(256, 4) void prop_pass(const unsigned short* __restrict__ gswz,
                                                    const unsigned short* __restrict__ hFin,
                                                    const float* __restrict__ dinv,
                                                    unsigned short* __restrict__ hrow,
                                                    unsigned short* __restrict__ hFout) {
    __shared__ float buf[4][16][68];
    __shared__ unsigned short hsh[32][64];
    __shared__ float dl[32];
    PROP_MAIN()
    // hrow: coalesced bf16 store of 32x64
    {
        unsigned short* hp = hrow + ((size_t)b * NN + mk * 32) * ND;
#pragma unroll
        for (int e = 0; e < 8; ++e) {
            int idx = e * 256 + t;
            hp[idx] = hsh[idx >> 6][idx & 63];
        }
    }
    // hF: kc = mk, 256 short8 -> 1/thread, value = d_j * h_j
    {
        int c = t >> 6, ln = t & 63;
        int mm = ln & 15, qq = ln >> 4;
        float v[8];
#pragma unroll
        for (int j = 0; j < 8; ++j) {
            int lr = qq * 8 + j;                         // 0..31
            v[j] = dl[lr] * bf2f(hsh[lr][c * 16 + mm]);
        }
        *reinterpret_cast<short8*>(hFout + (size_t)b * HF_B + ((size_t)(mk * 4 + c) * 64 + ln) * 8) = pack8p(v);
    }
}

// K3: pass 3 + fused final linear: out = [x,h1,h2,h3] @ W^T + bias
__global__ __launch_bounds__(256, 4) void prop_final(const unsigned short* __restrict__ gswz,
                                                     const unsigned short* __restrict__ hFin,
                                                     const float* __restrict__ dinv,
                                                     const float* __restrict__ x,
                                                     const unsigned short* __restrict__ hrow1,
                                                     const unsigned short* __restrict__ hrow2,
                                                     const unsigned short* __restrict__ Wf,
                                                     const float* __restrict__ bias,
                                                     float* __restrict__ out) {
    __shared__ float buf[4][16][68];
    __shared__ unsigned short hsh[32][64];
    __shared__ float dl[32];
    PROP_MAIN()
    // epilogue: waves 0,1 -> tiles u=0,1 (32 MFMA each)
    if (w < 2) {
        int u = w;
        int grow = b * NN + mk * 32 + u * 16 + m;        // A row for this lane
        floatx4 facc[4];
#pragma unroll
        for (int c = 0; c < 4; ++c) facc[c] = (floatx4){0.f, 0.f, 0.f, 0.f};
#pragma unroll
        for (int p = 0; p < 4; ++p) {
#pragma unroll
            for (int ki = 0; ki < 2; ++ki) {
                short8 af;
                if (p == 0) {
                    const float* xp = x + (size_t)grow * ND + ki * 32 + q * 8;
                    float v[8];
#pragma unroll
                    for (int j = 0; j < 8; ++j) v[j] = xp[j];
                    af = pack8p(v);
                } else if (p == 1) {
                    af = *reinterpret_cast<const short8*>(hrow1 + (size_t)grow * ND + ki * 32 + q * 8);
                } else if (p == 2) {
                    af = *reinterpret_cast<const short8*>(hrow2 + (size_t)grow * ND + ki * 32 + q * 8);
                } else {
                    af = *reinterpret_cast<const short8*>(&hsh[u * 16 + m][ki * 32 + q * 8]);
                }
                int kc = p * 2 + ki;
#pragma unroll
                for (int c = 0; c < 4; ++c) {
                    short8 bf = *reinterpret_cast<const short8*>(Wf + ((size_t)(kc * 4 + c) * 64 + lane) * 8);
                    facc[c] = __builtin_amdgcn_mfma_f32_16x16x32_bf16(af, bf, facc[c], 0, 0, 0);
                }
            }
        }
#pragma unroll
        for (int c = 0; c < 4; ++c) {
            float bb = bias[c * 16 + m];
#pragma unroll
            for (int r = 0; r < 4; ++r) {
                int row = b * NN + mk * 32 + u * 16 + q * 4 + r;
                out[(size_t)row * ND + c * 16 + m] = facc[c][r] + bb;
            }
        }
    }
}

// ================================================================ launch
extern "C" void kernel_launch(void* const* d_in, const int* in_sizes, int n_in,
                              void* d_out, int out_size, void* d_ws, size_t ws_size,
                              hipStream_t stream) {
    const float* x     = (const float*)d_in[0];
    const float* graph = (const float*)d_in[1];
    const float* W     = (const float*)d_in[2];
    const float* bias  = (const float*)d_in[3];
    float* out = (float*)d_out;

    // workspace layout (bytes)
    char* wsp = (char*)d_ws;
    float*          dinv  = (float*)wsp;                         //  64 KB
    unsigned short* Wf    = (unsigned short*)(wsp + (1 << 16));  //  16 KB
    unsigned short* hFa   = (unsigned short*)(wsp + (1 << 17));  //   2 MB
    unsigned short* hFb   = hFa + (size_t)NB * HF_B;             //   2 MB
    unsigned short* hrow1 = hFb + (size_t)NB * HF_B;             //   2 MB
    unsigned short* hrow2 = hrow1 + (size_t)NB * NN * ND;        //   2 MB
    unsigned short* gswz  = hrow2 + (size_t)NB * NN * ND;        // 134 MB

    prep_graph<<<1024, 256, 0, stream>>>(graph, x, W, dinv, gswz, hFa, Wf);
    prop_pass<<<512, 256, 0, stream>>>(gswz, hFa, dinv, hrow1, hFb);
    prop_pass<<<512, 256, 0, stream>>>(gswz, hFb, dinv, hrow2, hFa);
    prop_final<<<512, 256, 0, stream>>>(gswz, hFa, dinv, x, hrow1, hrow2, Wf, bias, out);
}